// Round 4
// baseline (140.539 us; speedup 1.0000x reference)
//
#include <hip/hip_runtime.h>
#include <hip/hip_bf16.h>

// Problem constants
#define BATCH 2
#define CH 256
#define NH 8
#define HD 32
#define NPOS 2304            // 48*48
#define SCALE 0.17677669529663687f          // 32^-0.5
#define QSCALE 0.25503482f                  // SCALE * log2(e)
#define NSPLIT 2
#define KSPAN (NPOS / NSPLIT)               // 1152
#define QT (NPOS / 16)                      // 144 q-tiles

typedef __attribute__((ext_vector_type(8))) short short8;   // 8 x bf16 (4 VGPRs)
typedef __attribute__((ext_vector_type(4))) short short4e;  // 4 x bf16 (8B)
typedef __attribute__((ext_vector_type(4))) float f32x4;

__device__ __forceinline__ unsigned short f2bf(float f) {
    unsigned int u = __builtin_bit_cast(unsigned int, f);
    u += 0x7FFFu + ((u >> 16) & 1u);     // round-to-nearest-even
    return (unsigned short)(u >> 16);
}

// ---------------------------------------------------------------------------
// Convert 4 fp32 [256x256] weight matrices to bf16 (concatenated dst).
// ---------------------------------------------------------------------------
__global__ __launch_bounds__(256) void convert_w(
    const float* __restrict__ Wq, const float* __restrict__ Wk,
    const float* __restrict__ Wv, const float* __restrict__ Wo,
    unsigned short* __restrict__ dst)
{
    int which = blockIdx.y;
    const float* src = (which == 0) ? Wq : (which == 1) ? Wk : (which == 2) ? Wv : Wo;
    unsigned short* d = dst + (size_t)which * CH * CH;
    int i = (blockIdx.x * 256 + threadIdx.x) * 4;
    f32x4 v = *(const f32x4*)&src[i];
    short4e o;
    #pragma unroll
    for (int j = 0; j < 4; ++j) o[j] = (short)f2bf(v[j]);
    *(short4e*)&d[i] = o;
}

// ---------------------------------------------------------------------------
// Transpose+convert: x fp32 [B][C][N] -> xT bf16 [B][N][C].
// ---------------------------------------------------------------------------
__global__ __launch_bounds__(256) void transpose_x(
    const float* __restrict__ x, unsigned short* __restrict__ xT)
{
    int b = blockIdx.z, c0 = blockIdx.y * 32, n0 = blockIdx.x * 32;
    __shared__ float Ts[32][33];
    int t = threadIdx.x;
    int col = t & 31, row = t >> 5;      // row 0..7
    #pragma unroll
    for (int i = 0; i < 4; ++i)
        Ts[row + i * 8][col] = x[((size_t)b * CH + c0 + row + i * 8) * NPOS + n0 + col];
    __syncthreads();
    #pragma unroll
    for (int i = 0; i < 4; ++i)
        xT[((size_t)b * NPOS + n0 + row + i * 8) * CH + c0 + col] = f2bf(Ts[col][row + i * 8]);
}

// ---------------------------------------------------------------------------
// Fused QKV GEMM via bf16 MFMA. xT: [B][N][C] bf16. Wb: q|k|v bf16 [o][c].
// q,k bf16 [(b*NH+h)*N + n]*32 + d   (q pre-scaled by QSCALE = SCALE*log2e)
// v  bf16 [(b*NH+h)*32 + d]*N + n    (transposed)
// ---------------------------------------------------------------------------
__global__ __launch_bounds__(256) void qkv_gemm(
    const unsigned short* __restrict__ xT,
    const unsigned short* __restrict__ Wb,
    const float* __restrict__ bq, const float* __restrict__ bk,
    const float* __restrict__ bv,
    unsigned short* __restrict__ qout, unsigned short* __restrict__ kout,
    unsigned short* __restrict__ vout)
{
    int b = blockIdx.z;
    int n0 = blockIdx.x * 64;
    int o0 = blockIdx.y * 64;
    int t = threadIdx.x, w = t >> 6, lane = t & 63;
    int lo = lane & 15, hi = lane >> 4;
    int ob = o0 + w * 16;

    const unsigned short* Wq = Wb;
    const unsigned short* Wk = Wb + (size_t)CH * CH;
    const unsigned short* Wv = Wb + (size_t)2 * CH * CH;
    const unsigned short* xb = xT + ((size_t)b * NPOS + n0) * CH;

    f32x4 aq[4] = {}, ak[4] = {}, av[4] = {};

    for (int k0 = 0; k0 < CH; k0 += 32) {
        short8 wqf = *(const short8*)&Wq[(size_t)(ob + lo) * CH + k0 + hi * 8];
        short8 wkf = *(const short8*)&Wk[(size_t)(ob + lo) * CH + k0 + hi * 8];
        short8 wvf = *(const short8*)&Wv[(size_t)(ob + lo) * CH + k0 + hi * 8];
        #pragma unroll
        for (int g = 0; g < 4; ++g) {
            short8 xf = *(const short8*)&xb[(size_t)(g * 16 + lo) * CH + k0 + hi * 8];
            aq[g] = __builtin_amdgcn_mfma_f32_16x16x32_bf16(wqf, xf, aq[g], 0, 0, 0);
            ak[g] = __builtin_amdgcn_mfma_f32_16x16x32_bf16(wkf, xf, ak[g], 0, 0, 0);
            av[g] = __builtin_amdgcn_mfma_f32_16x16x32_bf16(wvf, xf, av[g], 0, 0, 0);
        }
    }

    int h = ob >> 5;
    int olow = (ob & 31) + hi * 4;
    #pragma unroll
    for (int g = 0; g < 4; ++g) {
        int n = n0 + g * 16 + lo;
        size_t qkbase = ((size_t)(b * NH + h) * NPOS + n) * HD + olow;
        short4e pq, pk;
        #pragma unroll
        for (int r = 0; r < 4; ++r) {
            int o = ob + hi * 4 + r;
            pq[r] = (short)f2bf((aq[g][r] + bq[o]) * QSCALE);
            pk[r] = (short)f2bf(ak[g][r] + bk[o]);
        }
        *(short4e*)&qout[qkbase] = pq;
        *(short4e*)&kout[qkbase] = pk;
        size_t vbase = ((size_t)(b * NH + h) * HD + olow) * NPOS + n;
        #pragma unroll
        for (int r = 0; r < 4; ++r)
            vout[vbase + (size_t)r * NPOS] = f2bf(av[g][r] + bv[ob + hi * 4 + r]);
    }
}

// ---------------------------------------------------------------------------
// Flash attention partial, bf16 MFMA, 128-key tiles, split-K x2.
// No max-subtract (inputs bounded; softmax shift-invariant; Q carries log2e).
// P = exp2(S); row-sum l via ones-B MFMA. No cross-lane ops in the loop.
// Partial outputs: Opart f32 [bh][qt][split][d=32][row=16] (unnormalized),
//                  Lpart f32 [bh][qt][split][row=16].
// One wave per block; P-LDS double-buffered (wave-private, no barriers).
// ---------------------------------------------------------------------------
__global__ __launch_bounds__(64) void attn_split(
    const unsigned short* __restrict__ Q,
    const unsigned short* __restrict__ K,
    const unsigned short* __restrict__ V,
    float* __restrict__ Opart,
    float* __restrict__ Lpart)
{
    const int N = NPOS;
    int bh = blockIdx.z;            // 0..15
    int split = blockIdx.y;         // 0..NSPLIT-1
    int qt = blockIdx.x;            // 0..143
    int n0 = qt * 16;
    int lane = threadIdx.x & 63;
    int lo = lane & 15, hi = lane >> 4;

    __shared__ unsigned short Pl[2][2048];   // 2 x (16 rows x 128 keys) bf16

    short8 qa = *(const short8*)(Q + ((size_t)bh * N + n0 + lo) * HD + hi * 8);

    const unsigned short* Kb = K + (size_t)bh * N * HD;
    const unsigned short* Vb = V + (size_t)bh * HD * N;

    // bf16 1.0 = 0x3F80
    short8 ones;
    #pragma unroll
    for (int j = 0; j < 8; ++j) ones[j] = (short)0x3F80;

    f32x4 oacc[2] = {{0.f,0.f,0.f,0.f},{0.f,0.f,0.f,0.f}};
    f32x4 lacc = {0.f,0.f,0.f,0.f};

    const int kbeg = split * KSPAN;
    for (int kt = 0; kt < KSPAN / 128; ++kt) {
        int k0 = kbeg + kt * 128;
        int buf = kt & 1;
        // ---- S = Q K^T (log2 domain): 8 MFMAs
        f32x4 s[8];
        #pragma unroll
        for (int g = 0; g < 8; ++g) {
            short8 kf = *(const short8*)(Kb + (size_t)(k0 + g * 16 + lo) * HD + hi * 8);
            s[g] = __builtin_amdgcn_mfma_f32_16x16x32_bf16(qa, kf, (f32x4){0.f,0.f,0.f,0.f}, 0, 0, 0);
        }
        // ---- P = 2^S (no max shift)
        #pragma unroll
        for (int g = 0; g < 8; ++g)
            #pragma unroll
            for (int r = 0; r < 4; ++r)
                s[g][r] = exp2f(s[g][r]);

        // ---- P -> LDS bf16, swizzle: 16B-block index ^= (row&7)
        #pragma unroll
        for (int g = 0; g < 8; ++g) {
            int blk = g * 2 + (lo >> 3);
            #pragma unroll
            for (int r = 0; r < 4; ++r) {
                int row = hi * 4 + r;
                Pl[buf][row * 128 + ((blk ^ (row & 7)) * 8) + (lo & 7)] = f2bf(s[g][r]);
            }
        }

        // ---- O += P V ; l += P . 1
        #pragma unroll
        for (int c = 0; c < 4; ++c) {
            short8 pa = *(const short8*)&Pl[buf][lo * 128 + (((c * 4 + hi) ^ (lo & 7)) * 8)];
            lacc = __builtin_amdgcn_mfma_f32_16x16x32_bf16(pa, ones, lacc, 0, 0, 0);
            #pragma unroll
            for (int df = 0; df < 2; ++df) {
                short8 vf = *(const short8*)(Vb + (size_t)(df * 16 + lo) * N + k0 + c * 32 + hi * 8);
                oacc[df] = __builtin_amdgcn_mfma_f32_16x16x32_bf16(pa, vf, oacc[df], 0, 0, 0);
            }
        }
    }

    // ---- store partials (unnormalized). Opart tile layout [d=32][row=16].
    size_t tidx  = (((size_t)bh * QT + qt) * NSPLIT + split);
    float* ob = Opart + tidx * (HD * 16);
    #pragma unroll
    for (int df = 0; df < 2; ++df)
        *(f32x4*)&ob[(df * 16 + lo) * 16 + hi * 4] = oacc[df];
    if (lo == 0) {
        float* lb = Lpart + tidx * 16;
        #pragma unroll
        for (int r = 0; r < 4; ++r) lb[hi * 4 + r] = lacc[r];
    }
}

// ---------------------------------------------------------------------------
// Merge split-K partials: omT[b][n][h*32+d] = sum_s Opart / sum_s Lpart.
// grid (QT, 16), block 256: thread handles (d, row) and (d, row+8).
// ---------------------------------------------------------------------------
__global__ __launch_bounds__(256) void attn_merge(
    const float* __restrict__ Opart,
    const float* __restrict__ Lpart,
    unsigned short* __restrict__ omT)
{
    int bh = blockIdx.y, b = bh >> 3, h = bh & 7;
    int qt = blockIdx.x, n0 = qt * 16;
    int t = threadIdx.x;
    int d = t & 31;
    int r0 = t >> 5;                 // 0..7
    size_t base = ((size_t)bh * QT + qt) * NSPLIT;
    #pragma unroll
    for (int i = 0; i < 2; ++i) {
        int row = r0 + i * 8;
        float osum = 0.f, lsum = 0.f;
        #pragma unroll
        for (int s = 0; s < NSPLIT; ++s) {
            osum += Opart[(base + s) * (HD * 16) + d * 16 + row];
            lsum += Lpart[(base + s) * 16 + row];
        }
        omT[((size_t)b * NPOS + n0 + row) * CH + h * HD + d] = f2bf(osum / lsum);
    }
}

// ---------------------------------------------------------------------------
// Wo GEMM via bf16 MFMA: out fp32 [B][C][N] = Wo . omT^T + bo.
// ---------------------------------------------------------------------------
__global__ __launch_bounds__(256) void wo_gemm(
    const unsigned short* __restrict__ omT,
    const unsigned short* __restrict__ Wo,
    const float* __restrict__ bo,
    float* __restrict__ out)
{
    int b = blockIdx.z;
    int n0 = blockIdx.x * 64;
    int o0 = blockIdx.y * 64;
    int t = threadIdx.x, w = t >> 6, lane = t & 63;
    int lo = lane & 15, hi = lane >> 4;
    int ob = o0 + w * 16;

    const unsigned short* xb = omT + ((size_t)b * NPOS + n0) * CH;

    f32x4 acc[4] = {};
    for (int k0 = 0; k0 < CH; k0 += 32) {
        short8 wf = *(const short8*)&Wo[(size_t)(ob + lo) * CH + k0 + hi * 8];
        #pragma unroll
        for (int g = 0; g < 4; ++g) {
            short8 xf = *(const short8*)&xb[(size_t)(g * 16 + lo) * CH + k0 + hi * 8];
            acc[g] = __builtin_amdgcn_mfma_f32_16x16x32_bf16(wf, xf, acc[g], 0, 0, 0);
        }
    }

    #pragma unroll
    for (int g = 0; g < 4; ++g) {
        int n = n0 + g * 16 + lo;
        #pragma unroll
        for (int r = 0; r < 4; ++r) {
            int o = ob + hi * 4 + r;
            out[((size_t)b * CH + o) * NPOS + n] = acc[g][r] + bo[o];
        }
    }
}

// ---------------------------------------------------------------------------
extern "C" void kernel_launch(void* const* d_in, const int* in_sizes, int n_in,
                              void* d_out, int out_size, void* d_ws, size_t ws_size,
                              hipStream_t stream) {
    const float* x  = (const float*)d_in[0];
    const float* Wq = (const float*)d_in[1];
    const float* bq = (const float*)d_in[2];
    const float* Wk = (const float*)d_in[3];
    const float* bk = (const float*)d_in[4];
    const float* Wv = (const float*)d_in[5];
    const float* bv = (const float*)d_in[6];
    const float* Wo = (const float*)d_in[7];
    const float* bo = (const float*)d_in[8];
    float* out = (float*)d_out;

    const size_t E  = (size_t)BATCH * CH * NPOS;   // 1,179,648
    const size_t WS = (size_t)CH * CH;             // 65,536
    unsigned short* wbf = (unsigned short*)d_ws;   // 4 weight matrices bf16
    unsigned short* xT  = wbf + 4 * WS;            // [B][N][C] bf16
    unsigned short* qb  = xT + E;                  // [bh][N][32] bf16 (QSCALE'd)
    unsigned short* kb  = qb + E;                  // [bh][N][32] bf16
    unsigned short* vT  = kb + E;                  // [bh][32][N] bf16
    float* Opart = (float*)(vT + E);               // 16*144*NSPLIT*512 f32
    float* Lpart = Opart + (size_t)16 * QT * NSPLIT * (HD * 16);
    unsigned short* om = xT;                       // alias: xT dead after qkv_gemm
    (void)ws_size; (void)in_sizes; (void)n_in; (void)out_size;

    hipLaunchKernelGGL(convert_w, dim3(64, 4), dim3(256), 0, stream,
                       Wq, Wk, Wv, Wo, wbf);
    hipLaunchKernelGGL(transpose_x, dim3(NPOS / 32, CH / 32, BATCH), dim3(256), 0, stream,
                       x, xT);
    hipLaunchKernelGGL(qkv_gemm, dim3(NPOS / 64, CH / 64, BATCH), dim3(256), 0, stream,
                       xT, wbf, bq, bk, bv, qb, kb, vT);
    hipLaunchKernelGGL(attn_split, dim3(QT, NSPLIT, BATCH * NH), dim3(64), 0, stream,
                       qb, kb, vT, Opart, Lpart);
    hipLaunchKernelGGL(attn_merge, dim3(QT, BATCH * NH), dim3(256), 0, stream,
                       Opart, Lpart, om);
    hipLaunchKernelGGL(wo_gemm, dim3(NPOS / 64, CH / 64, BATCH), dim3(256), 0, stream,
                       om, wbf + 3 * WS, bo, out);
}

// Round 5
// 108.856 us; speedup vs baseline: 1.2911x; 1.2911x over previous
//
#include <hip/hip_runtime.h>
#include <hip/hip_bf16.h>

// Problem constants
#define BATCH 2
#define CH 256
#define NH 8
#define HD 32
#define NPOS 2304            // 48*48
#define SCALE 0.17677669529663687f          // 32^-0.5
#define QSCALE 0.25503482f                  // SCALE * log2(e)
#define NSPLIT 3
#define KSPAN (NPOS / NSPLIT)               // 768 = 6 tiles of 128
#define QT (NPOS / 16)                      // 144 q-tiles

typedef __attribute__((ext_vector_type(8))) short short8;   // 8 x bf16 (4 VGPRs)
typedef __attribute__((ext_vector_type(4))) short short4e;  // 4 x bf16 (8B)
typedef __attribute__((ext_vector_type(4))) float f32x4;
typedef __attribute__((ext_vector_type(4))) unsigned int u32x4;

__device__ __forceinline__ unsigned short f2bf(float f) {
    unsigned int u = __builtin_bit_cast(unsigned int, f);
    u += 0x7FFFu + ((u >> 16) & 1u);     // round-to-nearest-even
    return (unsigned short)(u >> 16);
}

// packed 2xbf16 <- 2xf32 (D.lo = cvt(a), D.hi = cvt(b)), RNE
__device__ __forceinline__ unsigned int cvt_pk_bf16(float a, float b) {
    unsigned int r;
    asm("v_cvt_pk_bf16_f32 %0, %1, %2" : "=v"(r) : "v"(a), "v"(b));
    return r;
}

// ---------------------------------------------------------------------------
// Convert 4 fp32 [256x256] weight matrices to bf16 (concatenated dst).
// ---------------------------------------------------------------------------
__global__ __launch_bounds__(256) void convert_w(
    const float* __restrict__ Wq, const float* __restrict__ Wk,
    const float* __restrict__ Wv, const float* __restrict__ Wo,
    unsigned short* __restrict__ dst)
{
    int which = blockIdx.y;
    const float* src = (which == 0) ? Wq : (which == 1) ? Wk : (which == 2) ? Wv : Wo;
    unsigned short* d = dst + (size_t)which * CH * CH;
    int i = (blockIdx.x * 256 + threadIdx.x) * 4;
    f32x4 v = *(const f32x4*)&src[i];
    short4e o;
    #pragma unroll
    for (int j = 0; j < 4; ++j) o[j] = (short)f2bf(v[j]);
    *(short4e*)&d[i] = o;
}

// ---------------------------------------------------------------------------
// Transpose+convert: x fp32 [B][C][N] -> xT bf16 [B][N][C].
// ---------------------------------------------------------------------------
__global__ __launch_bounds__(256) void transpose_x(
    const float* __restrict__ x, unsigned short* __restrict__ xT)
{
    int b = blockIdx.z, c0 = blockIdx.y * 32, n0 = blockIdx.x * 32;
    __shared__ float Ts[32][33];
    int t = threadIdx.x;
    int col = t & 31, row = t >> 5;      // row 0..7
    #pragma unroll
    for (int i = 0; i < 4; ++i)
        Ts[row + i * 8][col] = x[((size_t)b * CH + c0 + row + i * 8) * NPOS + n0 + col];
    __syncthreads();
    #pragma unroll
    for (int i = 0; i < 4; ++i)
        xT[((size_t)b * NPOS + n0 + row + i * 8) * CH + c0 + col] = f2bf(Ts[col][row + i * 8]);
}

// ---------------------------------------------------------------------------
// Fused QKV GEMM via bf16 MFMA. xT: [B][N][C] bf16. Wb: q|k|v bf16 [o][c].
// q,k bf16 [(b*NH+h)*N + n]*32 + d   (q pre-scaled by QSCALE = SCALE*log2e)
// v  bf16 [(b*NH+h)*32 + d]*N + pi(n)   (transposed, key-permuted per 128-blk)
// The key permutation pi matches attn_split's in-register P fragment layout.
// ---------------------------------------------------------------------------
__global__ __launch_bounds__(256) void qkv_gemm(
    const unsigned short* __restrict__ xT,
    const unsigned short* __restrict__ Wb,
    const float* __restrict__ bq, const float* __restrict__ bk,
    const float* __restrict__ bv,
    unsigned short* __restrict__ qout, unsigned short* __restrict__ kout,
    unsigned short* __restrict__ vout)
{
    int b = blockIdx.z;
    int n0 = blockIdx.x * 64;
    int o0 = blockIdx.y * 64;
    int t = threadIdx.x, w = t >> 6, lane = t & 63;
    int lo = lane & 15, hi = lane >> 4;
    int ob = o0 + w * 16;

    const unsigned short* Wq = Wb;
    const unsigned short* Wk = Wb + (size_t)CH * CH;
    const unsigned short* Wv = Wb + (size_t)2 * CH * CH;
    const unsigned short* xb = xT + ((size_t)b * NPOS + n0) * CH;

    f32x4 aq[4] = {}, ak[4] = {}, av[4] = {};

    for (int k0 = 0; k0 < CH; k0 += 32) {
        short8 wqf = *(const short8*)&Wq[(size_t)(ob + lo) * CH + k0 + hi * 8];
        short8 wkf = *(const short8*)&Wk[(size_t)(ob + lo) * CH + k0 + hi * 8];
        short8 wvf = *(const short8*)&Wv[(size_t)(ob + lo) * CH + k0 + hi * 8];
        #pragma unroll
        for (int g = 0; g < 4; ++g) {
            short8 xf = *(const short8*)&xb[(size_t)(g * 16 + lo) * CH + k0 + hi * 8];
            aq[g] = __builtin_amdgcn_mfma_f32_16x16x32_bf16(wqf, xf, aq[g], 0, 0, 0);
            ak[g] = __builtin_amdgcn_mfma_f32_16x16x32_bf16(wkf, xf, ak[g], 0, 0, 0);
            av[g] = __builtin_amdgcn_mfma_f32_16x16x32_bf16(wvf, xf, av[g], 0, 0, 0);
        }
    }

    int h = ob >> 5;
    int olow = (ob & 31) + hi * 4;
    #pragma unroll
    for (int g = 0; g < 4; ++g) {
        int n = n0 + g * 16 + lo;
        size_t qkbase = ((size_t)(b * NH + h) * NPOS + n) * HD + olow;
        short4e pq, pk;
        #pragma unroll
        for (int r = 0; r < 4; ++r) {
            int o = ob + hi * 4 + r;
            pq[r] = (short)f2bf((aq[g][r] + bq[o]) * QSCALE);
            pk[r] = (short)f2bf(ak[g][r] + bk[o]);
        }
        *(short4e*)&qout[qkbase] = pq;
        *(short4e*)&kout[qkbase] = pk;

        // ---- V store with key permutation pi within the 128-block
        int off = n & 127;               // raw offset in 128-tile
        int G = off >> 4;                // attention key-group 0..7
        int his = lo >> 2, rr = lo & 3;
        int pi;
        if (G < 4) {
            pi = G * 32 + his * 8 + rr;
        } else {
            int gam = G & 3;
            pi = (his >= 2) ? (gam * 32 + (his - 2) * 8 + 4 + rr)
                            : ((gam ^ 1) * 32 + (his + 2) * 8 + 4 + rr);
        }
        int nperm = (n & ~127) | pi;
        size_t vbase = ((size_t)(b * NH + h) * HD + olow) * NPOS + nperm;
        #pragma unroll
        for (int r = 0; r < 4; ++r)
            vout[vbase + (size_t)r * NPOS] = f2bf(av[g][r] + bv[ob + hi * 4 + r]);
    }
}

// ---------------------------------------------------------------------------
// Flash attention partial, bf16 MFMA, 128-key tiles, split-K x3.
// Swapped QK^T (mfma(K,Q)) -> P lane-local per q-row; P->bf16 via cvt_pk;
// PV A-frags assembled in-register via one shfl_xor(32) per word, using the
// key permutation pi applied to V storage. No LDS, no barriers, no max-shift.
// Partials: Opart f32 [bh][qt][split][d=32][row=16], Lpart [..][16].
// ---------------------------------------------------------------------------
__global__ __launch_bounds__(64) void attn_split(
    const unsigned short* __restrict__ Q,
    const unsigned short* __restrict__ K,
    const unsigned short* __restrict__ V,
    float* __restrict__ Opart,
    float* __restrict__ Lpart)
{
    const int N = NPOS;
    int bh = blockIdx.z;            // 0..15
    int split = blockIdx.y;         // 0..NSPLIT-1
    int qt = blockIdx.x;            // 0..143
    int n0 = qt * 16;
    int lane = threadIdx.x & 63;
    int lo = lane & 15, hi = lane >> 4;
    bool upperhalf = lane >= 32;

    short8 qa = *(const short8*)(Q + ((size_t)bh * N + n0 + lo) * HD + hi * 8);

    const unsigned short* Kb = K + (size_t)bh * N * HD;
    const unsigned short* Vb = V + (size_t)bh * HD * N;

    short8 ones;
    #pragma unroll
    for (int j = 0; j < 8; ++j) ones[j] = (short)0x3F80;   // bf16 1.0

    f32x4 oacc[2] = {{0.f,0.f,0.f,0.f},{0.f,0.f,0.f,0.f}};
    f32x4 lacc = {0.f,0.f,0.f,0.f};

    const int kbeg = split * KSPAN;
    for (int kt = 0; kt < KSPAN / 128; ++kt) {
        int k0 = kbeg + kt * 128;
        // ---- S^T = K Q^T (swapped): lane (lo,hi) -> P[q=lo][key g*16+hi*4+r]
        f32x4 s[8];
        #pragma unroll
        for (int g = 0; g < 8; ++g) {
            short8 kf = *(const short8*)(Kb + (size_t)(k0 + g * 16 + lo) * HD + hi * 8);
            s[g] = __builtin_amdgcn_mfma_f32_16x16x32_bf16(kf, qa, (f32x4){0.f,0.f,0.f,0.f}, 0, 0, 0);
        }
        // ---- P = 2^S (no max shift; Q carries SCALE*log2e)
        #pragma unroll
        for (int g = 0; g < 8; ++g)
            #pragma unroll
            for (int r = 0; r < 4; ++r)
                s[g][r] = exp2f(s[g][r]);

        // ---- pack to bf16 pairs
        unsigned int pk0[8], pk1[8];
        #pragma unroll
        for (int g = 0; g < 8; ++g) {
            pk0[g] = cvt_pk_bf16(s[g][0], s[g][1]);
            pk1[g] = cvt_pk_bf16(s[g][2], s[g][3]);
        }

        // ---- assemble PV A-frags: own groups 0-3 + partner(lane^32) groups 4-7
        #pragma unroll
        for (int c = 0; c < 4; ++c) {
            unsigned int z0 = upperhalf ? pk0[4 + c] : pk0[4 + (c ^ 1)];
            unsigned int z1 = upperhalf ? pk1[4 + c] : pk1[4 + (c ^ 1)];
            unsigned int r0 = (unsigned int)__shfl_xor((int)z0, 32);
            unsigned int r1 = (unsigned int)__shfl_xor((int)z1, 32);
            u32x4 fv = {pk0[c], pk1[c], r0, r1};
            short8 frag = __builtin_bit_cast(short8, fv);

            lacc = __builtin_amdgcn_mfma_f32_16x16x32_bf16(frag, ones, lacc, 0, 0, 0);
            #pragma unroll
            for (int df = 0; df < 2; ++df) {
                short8 vf = *(const short8*)(Vb + (size_t)(df * 16 + lo) * N + k0 + c * 32 + hi * 8);
                oacc[df] = __builtin_amdgcn_mfma_f32_16x16x32_bf16(frag, vf, oacc[df], 0, 0, 0);
            }
        }
    }

    // ---- store partials (unnormalized). Opart tile layout [d=32][row=16].
    size_t tidx  = (((size_t)bh * QT + qt) * NSPLIT + split);
    float* ob = Opart + tidx * (HD * 16);
    #pragma unroll
    for (int df = 0; df < 2; ++df)
        *(f32x4*)&ob[(df * 16 + lo) * 16 + hi * 4] = oacc[df];
    if (lo == 0) {
        float* lb = Lpart + tidx * 16;
        #pragma unroll
        for (int r = 0; r < 4; ++r) lb[hi * 4 + r] = lacc[r];
    }
}

// ---------------------------------------------------------------------------
// Merge split-K partials: omT[b][n][h*32+d] = sum_s Opart / sum_s Lpart.
// ---------------------------------------------------------------------------
__global__ __launch_bounds__(256) void attn_merge(
    const float* __restrict__ Opart,
    const float* __restrict__ Lpart,
    unsigned short* __restrict__ omT)
{
    int bh = blockIdx.y, b = bh >> 3, h = bh & 7;
    int qt = blockIdx.x, n0 = qt * 16;
    int t = threadIdx.x;
    int d = t & 31;
    int r0 = t >> 5;                 // 0..7
    size_t base = ((size_t)bh * QT + qt) * NSPLIT;
    #pragma unroll
    for (int i = 0; i < 2; ++i) {
        int row = r0 + i * 8;
        float osum = 0.f, lsum = 0.f;
        #pragma unroll
        for (int s = 0; s < NSPLIT; ++s) {
            osum += Opart[(base + s) * (HD * 16) + d * 16 + row];
            lsum += Lpart[(base + s) * 16 + row];
        }
        omT[((size_t)b * NPOS + n0 + row) * CH + h * HD + d] = f2bf(osum / lsum);
    }
}

// ---------------------------------------------------------------------------
// Wo GEMM via bf16 MFMA: out fp32 [B][C][N] = Wo . omT^T + bo.
// ---------------------------------------------------------------------------
__global__ __launch_bounds__(256) void wo_gemm(
    const unsigned short* __restrict__ omT,
    const unsigned short* __restrict__ Wo,
    const float* __restrict__ bo,
    float* __restrict__ out)
{
    int b = blockIdx.z;
    int n0 = blockIdx.x * 64;
    int o0 = blockIdx.y * 64;
    int t = threadIdx.x, w = t >> 6, lane = t & 63;
    int lo = lane & 15, hi = lane >> 4;
    int ob = o0 + w * 16;

    const unsigned short* xb = omT + ((size_t)b * NPOS + n0) * CH;

    f32x4 acc[4] = {};
    for (int k0 = 0; k0 < CH; k0 += 32) {
        short8 wf = *(const short8*)&Wo[(size_t)(ob + lo) * CH + k0 + hi * 8];
        #pragma unroll
        for (int g = 0; g < 4; ++g) {
            short8 xf = *(const short8*)&xb[(size_t)(g * 16 + lo) * CH + k0 + hi * 8];
            acc[g] = __builtin_amdgcn_mfma_f32_16x16x32_bf16(wf, xf, acc[g], 0, 0, 0);
        }
    }

    #pragma unroll
    for (int g = 0; g < 4; ++g) {
        int n = n0 + g * 16 + lo;
        #pragma unroll
        for (int r = 0; r < 4; ++r) {
            int o = ob + hi * 4 + r;
            out[((size_t)b * CH + o) * NPOS + n] = acc[g][r] + bo[o];
        }
    }
}

// ---------------------------------------------------------------------------
extern "C" void kernel_launch(void* const* d_in, const int* in_sizes, int n_in,
                              void* d_out, int out_size, void* d_ws, size_t ws_size,
                              hipStream_t stream) {
    const float* x  = (const float*)d_in[0];
    const float* Wq = (const float*)d_in[1];
    const float* bq = (const float*)d_in[2];
    const float* Wk = (const float*)d_in[3];
    const float* bk = (const float*)d_in[4];
    const float* Wv = (const float*)d_in[5];
    const float* bv = (const float*)d_in[6];
    const float* Wo = (const float*)d_in[7];
    const float* bo = (const float*)d_in[8];
    float* out = (float*)d_out;

    const size_t E  = (size_t)BATCH * CH * NPOS;   // 1,179,648
    const size_t WS = (size_t)CH * CH;             // 65,536
    unsigned short* wbf = (unsigned short*)d_ws;   // 4 weight matrices bf16
    unsigned short* xT  = wbf + 4 * WS;            // [B][N][C] bf16
    unsigned short* qb  = xT + E;                  // [bh][N][32] bf16 (QSCALE'd)
    unsigned short* kb  = qb + E;                  // [bh][N][32] bf16
    unsigned short* vT  = kb + E;                  // [bh][32][N] bf16 (pi-permuted)
    float* Opart = (float*)(vT + E);               // 16*QT*NSPLIT*512 f32
    float* Lpart = Opart + (size_t)16 * QT * NSPLIT * (HD * 16);
    unsigned short* om = xT;                       // alias: xT dead after qkv_gemm
    (void)ws_size; (void)in_sizes; (void)n_in; (void)out_size;

    hipLaunchKernelGGL(convert_w, dim3(64, 4), dim3(256), 0, stream,
                       Wq, Wk, Wv, Wo, wbf);
    hipLaunchKernelGGL(transpose_x, dim3(NPOS / 32, CH / 32, BATCH), dim3(256), 0, stream,
                       x, xT);
    hipLaunchKernelGGL(qkv_gemm, dim3(NPOS / 64, CH / 64, BATCH), dim3(256), 0, stream,
                       xT, wbf, bq, bk, bv, qb, kb, vT);
    hipLaunchKernelGGL(attn_split, dim3(QT, NSPLIT, BATCH * NH), dim3(64), 0, stream,
                       qb, kb, vT, Opart, Lpart);
    hipLaunchKernelGGL(attn_merge, dim3(QT, BATCH * NH), dim3(256), 0, stream,
                       Opart, Lpart, om);
    hipLaunchKernelGGL(wo_gemm, dim3(NPOS / 64, CH / 64, BATCH), dim3(256), 0, stream,
                       om, wbf + 3 * WS, bo, out);
}

// Round 6
// 108.699 us; speedup vs baseline: 1.2929x; 1.0014x over previous
//
#include <hip/hip_runtime.h>
#include <hip/hip_bf16.h>

// Problem constants
#define BATCH 2
#define CH 256
#define NH 8
#define HD 32
#define NPOS 2304            // 48*48
#define SCALE 0.17677669529663687f          // 32^-0.5
#define QSCALE 0.25503482f                  // SCALE * log2(e)
#define NSPLIT 3
#define KSPAN (NPOS / NSPLIT)               // 768 = 6 tiles of 128
#define NT (KSPAN / 128)                    // 6
#define QT (NPOS / 16)                      // 144 q-tiles

typedef __attribute__((ext_vector_type(8))) short short8;   // 8 x bf16 (4 VGPRs)
typedef __attribute__((ext_vector_type(4))) short short4e;  // 4 x bf16 (8B)
typedef __attribute__((ext_vector_type(4))) float f32x4;
typedef __attribute__((ext_vector_type(4))) unsigned int u32x4;

__device__ __forceinline__ unsigned short f2bf(float f) {
    unsigned int u = __builtin_bit_cast(unsigned int, f);
    u += 0x7FFFu + ((u >> 16) & 1u);     // round-to-nearest-even
    return (unsigned short)(u >> 16);
}

// packed 2xbf16 <- 2xf32 (D.lo = cvt(a), D.hi = cvt(b)), RNE
__device__ __forceinline__ unsigned int cvt_pk_bf16(float a, float b) {
    unsigned int r;
    asm("v_cvt_pk_bf16_f32 %0, %1, %2" : "=v"(r) : "v"(a), "v"(b));
    return r;
}

// single-instruction 2^x (no libm edge handling)
__device__ __forceinline__ float fast_exp2(float x) {
    float r;
    asm("v_exp_f32 %0, %1" : "=v"(r) : "v"(x));
    return r;
}

// ---------------------------------------------------------------------------
// Convert 4 fp32 [256x256] weight matrices to bf16 (concatenated dst).
// ---------------------------------------------------------------------------
__global__ __launch_bounds__(256) void convert_w(
    const float* __restrict__ Wq, const float* __restrict__ Wk,
    const float* __restrict__ Wv, const float* __restrict__ Wo,
    unsigned short* __restrict__ dst)
{
    int which = blockIdx.y;
    const float* src = (which == 0) ? Wq : (which == 1) ? Wk : (which == 2) ? Wv : Wo;
    unsigned short* d = dst + (size_t)which * CH * CH;
    int i = (blockIdx.x * 256 + threadIdx.x) * 4;
    f32x4 v = *(const f32x4*)&src[i];
    short4e o;
    #pragma unroll
    for (int j = 0; j < 4; ++j) o[j] = (short)f2bf(v[j]);
    *(short4e*)&d[i] = o;
}

// ---------------------------------------------------------------------------
// Transpose+convert: x fp32 [B][C][N] -> xT bf16 [B][N][C].
// ---------------------------------------------------------------------------
__global__ __launch_bounds__(256) void transpose_x(
    const float* __restrict__ x, unsigned short* __restrict__ xT)
{
    int b = blockIdx.z, c0 = blockIdx.y * 32, n0 = blockIdx.x * 32;
    __shared__ float Ts[32][33];
    int t = threadIdx.x;
    int col = t & 31, row = t >> 5;      // row 0..7
    #pragma unroll
    for (int i = 0; i < 4; ++i)
        Ts[row + i * 8][col] = x[((size_t)b * CH + c0 + row + i * 8) * NPOS + n0 + col];
    __syncthreads();
    #pragma unroll
    for (int i = 0; i < 4; ++i)
        xT[((size_t)b * NPOS + n0 + row + i * 8) * CH + c0 + col] = f2bf(Ts[col][row + i * 8]);
}

// ---------------------------------------------------------------------------
// Fused QKV GEMM via bf16 MFMA. xT: [B][N][C] bf16. Wb: q|k|v bf16 [o][c].
// q,k bf16 [(b*NH+h)*N + n]*32 + d   (q pre-scaled by QSCALE = SCALE*log2e)
// v  bf16 [(b*NH+h)*32 + d]*N + pi(n)   (transposed, key-permuted per 128-blk)
// The key permutation pi matches attn_split's in-register P fragment layout.
// ---------------------------------------------------------------------------
__global__ __launch_bounds__(256) void qkv_gemm(
    const unsigned short* __restrict__ xT,
    const unsigned short* __restrict__ Wb,
    const float* __restrict__ bq, const float* __restrict__ bk,
    const float* __restrict__ bv,
    unsigned short* __restrict__ qout, unsigned short* __restrict__ kout,
    unsigned short* __restrict__ vout)
{
    int b = blockIdx.z;
    int n0 = blockIdx.x * 64;
    int o0 = blockIdx.y * 64;
    int t = threadIdx.x, w = t >> 6, lane = t & 63;
    int lo = lane & 15, hi = lane >> 4;
    int ob = o0 + w * 16;

    const unsigned short* Wq = Wb;
    const unsigned short* Wk = Wb + (size_t)CH * CH;
    const unsigned short* Wv = Wb + (size_t)2 * CH * CH;
    const unsigned short* xb = xT + ((size_t)b * NPOS + n0) * CH;

    f32x4 aq[4] = {}, ak[4] = {}, av[4] = {};

    for (int k0 = 0; k0 < CH; k0 += 32) {
        short8 wqf = *(const short8*)&Wq[(size_t)(ob + lo) * CH + k0 + hi * 8];
        short8 wkf = *(const short8*)&Wk[(size_t)(ob + lo) * CH + k0 + hi * 8];
        short8 wvf = *(const short8*)&Wv[(size_t)(ob + lo) * CH + k0 + hi * 8];
        #pragma unroll
        for (int g = 0; g < 4; ++g) {
            short8 xf = *(const short8*)&xb[(size_t)(g * 16 + lo) * CH + k0 + hi * 8];
            aq[g] = __builtin_amdgcn_mfma_f32_16x16x32_bf16(wqf, xf, aq[g], 0, 0, 0);
            ak[g] = __builtin_amdgcn_mfma_f32_16x16x32_bf16(wkf, xf, ak[g], 0, 0, 0);
            av[g] = __builtin_amdgcn_mfma_f32_16x16x32_bf16(wvf, xf, av[g], 0, 0, 0);
        }
    }

    int h = ob >> 5;
    int olow = (ob & 31) + hi * 4;
    #pragma unroll
    for (int g = 0; g < 4; ++g) {
        int n = n0 + g * 16 + lo;
        size_t qkbase = ((size_t)(b * NH + h) * NPOS + n) * HD + olow;
        short4e pq, pk;
        #pragma unroll
        for (int r = 0; r < 4; ++r) {
            int o = ob + hi * 4 + r;
            pq[r] = (short)f2bf((aq[g][r] + bq[o]) * QSCALE);
            pk[r] = (short)f2bf(ak[g][r] + bk[o]);
        }
        *(short4e*)&qout[qkbase] = pq;
        *(short4e*)&kout[qkbase] = pk;

        // ---- V store with key permutation pi within the 128-block
        int off = n & 127;               // raw offset in 128-tile
        int G = off >> 4;                // attention key-group 0..7
        int his = lo >> 2, rr = lo & 3;
        int pi;
        if (G < 4) {
            pi = G * 32 + his * 8 + rr;
        } else {
            int gam = G & 3;
            pi = (his >= 2) ? (gam * 32 + (his - 2) * 8 + 4 + rr)
                            : ((gam ^ 1) * 32 + (his + 2) * 8 + 4 + rr);
        }
        int nperm = (n & ~127) | pi;
        size_t vbase = ((size_t)(b * NH + h) * HD + olow) * NPOS + nperm;
        #pragma unroll
        for (int r = 0; r < 4; ++r)
            vout[vbase + (size_t)r * NPOS] = f2bf(av[g][r] + bv[ob + hi * 4 + r]);
    }
}

// ---------------------------------------------------------------------------
// Flash attention partial, bf16 MFMA, 128-key tiles, split-K x3.
// Swapped QK^T (mfma(K,Q)) -> P lane-local per q-row; P->bf16 via cvt_pk;
// PV A-frags assembled in-register via one shfl_xor(32) per word, using the
// key permutation pi applied to V storage. No LDS, no barriers, no max-shift.
// 4 waves/block, each wave a different q-tile with identical (split,bh):
// waves share the K/V stream (L1 reuse). Software-pipelined K prefetch.
// Partials: Opart f32 [bh][qt][split][d=32][row=16], Lpart [..][16].
// ---------------------------------------------------------------------------
__global__ __launch_bounds__(256) void attn_split(
    const unsigned short* __restrict__ Q,
    const unsigned short* __restrict__ K,
    const unsigned short* __restrict__ V,
    float* __restrict__ Opart,
    float* __restrict__ Lpart)
{
    const int N = NPOS;
    int bh = blockIdx.z;            // 0..15
    int split = blockIdx.y;         // 0..NSPLIT-1
    int w = threadIdx.x >> 6;
    int qt = blockIdx.x * 4 + w;    // 0..143
    int n0 = qt * 16;
    int lane = threadIdx.x & 63;
    int lo = lane & 15, hi = lane >> 4;
    bool upperhalf = lane >= 32;

    short8 qa = *(const short8*)(Q + ((size_t)bh * N + n0 + lo) * HD + hi * 8);

    const unsigned short* Kb = K + (size_t)bh * N * HD;
    const unsigned short* Vb = V + (size_t)bh * HD * N;

    short8 ones;
    #pragma unroll
    for (int j = 0; j < 8; ++j) ones[j] = (short)0x3F80;   // bf16 1.0

    f32x4 oacc[2] = {{0.f,0.f,0.f,0.f},{0.f,0.f,0.f,0.f}};
    f32x4 lacc = {0.f,0.f,0.f,0.f};

    const int kbeg = split * KSPAN;

    // prologue: K fragments for tile 0
    short8 kf[8];
    #pragma unroll
    for (int g = 0; g < 8; ++g)
        kf[g] = *(const short8*)(Kb + (size_t)(kbeg + g * 16 + lo) * HD + hi * 8);

    #pragma unroll
    for (int kt = 0; kt < NT; ++kt) {
        int k0 = kbeg + kt * 128;

        // ---- S^T = K Q^T (swapped): lane (lo,hi) -> P[q=lo][key g*16+hi*4+r]
        f32x4 s[8];
        __builtin_amdgcn_s_setprio(1);
        #pragma unroll
        for (int g = 0; g < 8; ++g)
            s[g] = __builtin_amdgcn_mfma_f32_16x16x32_bf16(kf[g], qa, (f32x4){0.f,0.f,0.f,0.f}, 0, 0, 0);
        __builtin_amdgcn_s_setprio(0);

        // ---- prefetch next tile's K fragments (hidden under exp2/cvt chain)
        if (kt + 1 < NT) {
            #pragma unroll
            for (int g = 0; g < 8; ++g)
                kf[g] = *(const short8*)(Kb + (size_t)(k0 + 128 + g * 16 + lo) * HD + hi * 8);
        }
        // ---- V fragments for the current tile (issued before VALU chain)
        short8 vf[4][2];
        #pragma unroll
        for (int c = 0; c < 4; ++c)
            #pragma unroll
            for (int df = 0; df < 2; ++df)
                vf[c][df] = *(const short8*)(Vb + (size_t)(df * 16 + lo) * N + k0 + c * 32 + hi * 8);

        // ---- P = 2^S (no max shift; Q carries SCALE*log2e)
        #pragma unroll
        for (int g = 0; g < 8; ++g)
            #pragma unroll
            for (int r = 0; r < 4; ++r)
                s[g][r] = fast_exp2(s[g][r]);

        // ---- pack to bf16 pairs
        unsigned int pk0[8], pk1[8];
        #pragma unroll
        for (int g = 0; g < 8; ++g) {
            pk0[g] = cvt_pk_bf16(s[g][0], s[g][1]);
            pk1[g] = cvt_pk_bf16(s[g][2], s[g][3]);
        }

        // ---- assemble PV A-frags: own groups 0-3 + partner(lane^32) groups 4-7
        #pragma unroll
        for (int c = 0; c < 4; ++c) {
            unsigned int z0 = upperhalf ? pk0[4 + c] : pk0[4 + (c ^ 1)];
            unsigned int z1 = upperhalf ? pk1[4 + c] : pk1[4 + (c ^ 1)];
            unsigned int r0 = (unsigned int)__shfl_xor((int)z0, 32);
            unsigned int r1 = (unsigned int)__shfl_xor((int)z1, 32);
            u32x4 fv = {pk0[c], pk1[c], r0, r1};
            short8 frag = __builtin_bit_cast(short8, fv);

            __builtin_amdgcn_s_setprio(1);
            lacc = __builtin_amdgcn_mfma_f32_16x16x32_bf16(frag, ones, lacc, 0, 0, 0);
            oacc[0] = __builtin_amdgcn_mfma_f32_16x16x32_bf16(frag, vf[c][0], oacc[0], 0, 0, 0);
            oacc[1] = __builtin_amdgcn_mfma_f32_16x16x32_bf16(frag, vf[c][1], oacc[1], 0, 0, 0);
            __builtin_amdgcn_s_setprio(0);
        }
    }

    // ---- store partials (unnormalized). Opart tile layout [d=32][row=16].
    size_t tidx  = (((size_t)bh * QT + qt) * NSPLIT + split);
    float* ob = Opart + tidx * (HD * 16);
    #pragma unroll
    for (int df = 0; df < 2; ++df)
        *(f32x4*)&ob[(df * 16 + lo) * 16 + hi * 4] = oacc[df];
    if (lo == 0) {
        float* lb = Lpart + tidx * 16;
        #pragma unroll
        for (int r = 0; r < 4; ++r) lb[hi * 4 + r] = lacc[r];
    }
}

// ---------------------------------------------------------------------------
// Merge split-K partials: omT[b][n][h*32+d] = sum_s Opart / sum_s Lpart.
// ---------------------------------------------------------------------------
__global__ __launch_bounds__(256) void attn_merge(
    const float* __restrict__ Opart,
    const float* __restrict__ Lpart,
    unsigned short* __restrict__ omT)
{
    int bh = blockIdx.y, b = bh >> 3, h = bh & 7;
    int qt = blockIdx.x, n0 = qt * 16;
    int t = threadIdx.x;
    int d = t & 31;
    int r0 = t >> 5;                 // 0..7
    size_t base = ((size_t)bh * QT + qt) * NSPLIT;
    #pragma unroll
    for (int i = 0; i < 2; ++i) {
        int row = r0 + i * 8;
        float osum = 0.f, lsum = 0.f;
        #pragma unroll
        for (int s = 0; s < NSPLIT; ++s) {
            osum += Opart[(base + s) * (HD * 16) + d * 16 + row];
            lsum += Lpart[(base + s) * 16 + row];
        }
        omT[((size_t)b * NPOS + n0 + row) * CH + h * HD + d] = f2bf(osum / lsum);
    }
}

// ---------------------------------------------------------------------------
// Wo GEMM via bf16 MFMA: out fp32 [B][C][N] = Wo . omT^T + bo.
// ---------------------------------------------------------------------------
__global__ __launch_bounds__(256) void wo_gemm(
    const unsigned short* __restrict__ omT,
    const unsigned short* __restrict__ Wo,
    const float* __restrict__ bo,
    float* __restrict__ out)
{
    int b = blockIdx.z;
    int n0 = blockIdx.x * 64;
    int o0 = blockIdx.y * 64;
    int t = threadIdx.x, w = t >> 6, lane = t & 63;
    int lo = lane & 15, hi = lane >> 4;
    int ob = o0 + w * 16;

    const unsigned short* xb = omT + ((size_t)b * NPOS + n0) * CH;

    f32x4 acc[4] = {};
    for (int k0 = 0; k0 < CH; k0 += 32) {
        short8 wf = *(const short8*)&Wo[(size_t)(ob + lo) * CH + k0 + hi * 8];
        #pragma unroll
        for (int g = 0; g < 4; ++g) {
            short8 xf = *(const short8*)&xb[(size_t)(g * 16 + lo) * CH + k0 + hi * 8];
            acc[g] = __builtin_amdgcn_mfma_f32_16x16x32_bf16(wf, xf, acc[g], 0, 0, 0);
        }
    }

    #pragma unroll
    for (int g = 0; g < 4; ++g) {
        int n = n0 + g * 16 + lo;
        #pragma unroll
        for (int r = 0; r < 4; ++r) {
            int o = ob + hi * 4 + r;
            out[((size_t)b * CH + o) * NPOS + n] = acc[g][r] + bo[o];
        }
    }
}

// ---------------------------------------------------------------------------
extern "C" void kernel_launch(void* const* d_in, const int* in_sizes, int n_in,
                              void* d_out, int out_size, void* d_ws, size_t ws_size,
                              hipStream_t stream) {
    const float* x  = (const float*)d_in[0];
    const float* Wq = (const float*)d_in[1];
    const float* bq = (const float*)d_in[2];
    const float* Wk = (const float*)d_in[3];
    const float* bk = (const float*)d_in[4];
    const float* Wv = (const float*)d_in[5];
    const float* bv = (const float*)d_in[6];
    const float* Wo = (const float*)d_in[7];
    const float* bo = (const float*)d_in[8];
    float* out = (float*)d_out;

    const size_t E  = (size_t)BATCH * CH * NPOS;   // 1,179,648
    const size_t WS = (size_t)CH * CH;             // 65,536
    unsigned short* wbf = (unsigned short*)d_ws;   // 4 weight matrices bf16
    unsigned short* xT  = wbf + 4 * WS;            // [B][N][C] bf16
    unsigned short* qb  = xT + E;                  // [bh][N][32] bf16 (QSCALE'd)
    unsigned short* kb  = qb + E;                  // [bh][N][32] bf16
    unsigned short* vT  = kb + E;                  // [bh][32][N] bf16 (pi-permuted)
    float* Opart = (float*)(vT + E);               // 16*QT*NSPLIT*512 f32
    float* Lpart = Opart + (size_t)16 * QT * NSPLIT * (HD * 16);
    unsigned short* om = xT;                       // alias: xT dead after qkv_gemm
    (void)ws_size; (void)in_sizes; (void)n_in; (void)out_size;

    hipLaunchKernelGGL(convert_w, dim3(64, 4), dim3(256), 0, stream,
                       Wq, Wk, Wv, Wo, wbf);
    hipLaunchKernelGGL(transpose_x, dim3(NPOS / 32, CH / 32, BATCH), dim3(256), 0, stream,
                       x, xT);
    hipLaunchKernelGGL(qkv_gemm, dim3(NPOS / 64, CH / 64, BATCH), dim3(256), 0, stream,
                       xT, wbf, bq, bk, bv, qb, kb, vT);
    hipLaunchKernelGGL(attn_split, dim3(QT / 4, NSPLIT, BATCH * NH), dim3(256), 0, stream,
                       qb, kb, vT, Opart, Lpart);
    hipLaunchKernelGGL(attn_merge, dim3(QT, BATCH * NH), dim3(256), 0, stream,
                       Opart, Lpart, om);
    hipLaunchKernelGGL(wo_gemm, dim3(NPOS / 64, CH / 64, BATCH), dim3(256), 0, stream,
                       om, wbf + 3 * WS, bo, out);
}

// Round 7
// 75.761 us; speedup vs baseline: 1.8550x; 1.4348x over previous
//
#include <hip/hip_runtime.h>
#include <hip/hip_bf16.h>

// Problem constants
#define BATCH 2
#define CH 256
#define NH 8
#define HD 32
#define NPOS 2304            // 48*48
#define SCALE 0.17677669529663687f          // 32^-0.5
#define QSCALE 0.25503482f                  // SCALE * log2(e)
#define NSPLIT 3
#define KSPAN (NPOS / NSPLIT)               // 768 = 6 tiles of 128
#define NT (KSPAN / 128)                    // 6
#define QT (NPOS / 16)                      // 144 q-tiles

typedef __attribute__((ext_vector_type(8))) short short8;   // 8 x bf16 (4 VGPRs)
typedef __attribute__((ext_vector_type(4))) short short4e;  // 4 x bf16 (8B)
typedef __attribute__((ext_vector_type(4))) float f32x4;
typedef __attribute__((ext_vector_type(4))) unsigned int u32x4;

__device__ __forceinline__ unsigned short f2bf(float f) {
    unsigned int u = __builtin_bit_cast(unsigned int, f);
    u += 0x7FFFu + ((u >> 16) & 1u);     // round-to-nearest-even
    return (unsigned short)(u >> 16);
}

// packed 2xbf16 <- 2xf32 (D.lo = cvt(a), D.hi = cvt(b)), RNE
__device__ __forceinline__ unsigned int cvt_pk_bf16(float a, float b) {
    unsigned int r;
    asm("v_cvt_pk_bf16_f32 %0, %1, %2" : "=v"(r) : "v"(a), "v"(b));
    return r;
}

// single-instruction 2^x
__device__ __forceinline__ float fast_exp2(float x) {
    float r;
    asm("v_exp_f32 %0, %1" : "=v"(r) : "v"(x));
    return r;
}

// async global->LDS, 16B per lane; LDS dest = uniform base + lane*16
#define GLOAD_LDS16(gsrc, ldst) \
    __builtin_amdgcn_global_load_lds( \
        (const __attribute__((address_space(1))) void*)(gsrc), \
        (__attribute__((address_space(3))) void*)(ldst), 16, 0, 0)

// ---------------------------------------------------------------------------
// Convert 4 fp32 [256x256] weight matrices to bf16 (concatenated dst).
// ---------------------------------------------------------------------------
__global__ __launch_bounds__(256) void convert_w(
    const float* __restrict__ Wq, const float* __restrict__ Wk,
    const float* __restrict__ Wv, const float* __restrict__ Wo,
    unsigned short* __restrict__ dst)
{
    int which = blockIdx.y;
    const float* src = (which == 0) ? Wq : (which == 1) ? Wk : (which == 2) ? Wv : Wo;
    unsigned short* d = dst + (size_t)which * CH * CH;
    int i = (blockIdx.x * 256 + threadIdx.x) * 4;
    f32x4 v = *(const f32x4*)&src[i];
    short4e o;
    #pragma unroll
    for (int j = 0; j < 4; ++j) o[j] = (short)f2bf(v[j]);
    *(short4e*)&d[i] = o;
}

// ---------------------------------------------------------------------------
// Transpose+convert: x fp32 [B][C][N] -> xT bf16 [B][N][C].
// ---------------------------------------------------------------------------
__global__ __launch_bounds__(256) void transpose_x(
    const float* __restrict__ x, unsigned short* __restrict__ xT)
{
    int b = blockIdx.z, c0 = blockIdx.y * 32, n0 = blockIdx.x * 32;
    __shared__ float Ts[32][33];
    int t = threadIdx.x;
    int col = t & 31, row = t >> 5;      // row 0..7
    #pragma unroll
    for (int i = 0; i < 4; ++i)
        Ts[row + i * 8][col] = x[((size_t)b * CH + c0 + row + i * 8) * NPOS + n0 + col];
    __syncthreads();
    #pragma unroll
    for (int i = 0; i < 4; ++i)
        xT[((size_t)b * NPOS + n0 + row + i * 8) * CH + c0 + col] = f2bf(Ts[col][row + i * 8]);
}

// ---------------------------------------------------------------------------
// Fused QKV GEMM via bf16 MFMA. xT: [B][N][C] bf16. Wb: q|k|v bf16 [o][c].
// q,k bf16 [(b*NH+h)*N + n]*32 + d   (q pre-scaled by QSCALE = SCALE*log2e)
// v  bf16 [(b*NH+h)*32 + d]*N + pi(n)   (transposed, key-permuted per 128-blk)
// The key permutation pi matches attn_split's in-register P fragment layout.
// ---------------------------------------------------------------------------
__global__ __launch_bounds__(256) void qkv_gemm(
    const unsigned short* __restrict__ xT,
    const unsigned short* __restrict__ Wb,
    const float* __restrict__ bq, const float* __restrict__ bk,
    const float* __restrict__ bv,
    unsigned short* __restrict__ qout, unsigned short* __restrict__ kout,
    unsigned short* __restrict__ vout)
{
    int b = blockIdx.z;
    int n0 = blockIdx.x * 64;
    int o0 = blockIdx.y * 64;
    int t = threadIdx.x, w = t >> 6, lane = t & 63;
    int lo = lane & 15, hi = lane >> 4;
    int ob = o0 + w * 16;

    const unsigned short* Wq = Wb;
    const unsigned short* Wk = Wb + (size_t)CH * CH;
    const unsigned short* Wv = Wb + (size_t)2 * CH * CH;
    const unsigned short* xb = xT + ((size_t)b * NPOS + n0) * CH;

    f32x4 aq[4] = {}, ak[4] = {}, av[4] = {};

    for (int k0 = 0; k0 < CH; k0 += 32) {
        short8 wqf = *(const short8*)&Wq[(size_t)(ob + lo) * CH + k0 + hi * 8];
        short8 wkf = *(const short8*)&Wk[(size_t)(ob + lo) * CH + k0 + hi * 8];
        short8 wvf = *(const short8*)&Wv[(size_t)(ob + lo) * CH + k0 + hi * 8];
        #pragma unroll
        for (int g = 0; g < 4; ++g) {
            short8 xf = *(const short8*)&xb[(size_t)(g * 16 + lo) * CH + k0 + hi * 8];
            aq[g] = __builtin_amdgcn_mfma_f32_16x16x32_bf16(wqf, xf, aq[g], 0, 0, 0);
            ak[g] = __builtin_amdgcn_mfma_f32_16x16x32_bf16(wkf, xf, ak[g], 0, 0, 0);
            av[g] = __builtin_amdgcn_mfma_f32_16x16x32_bf16(wvf, xf, av[g], 0, 0, 0);
        }
    }

    int h = ob >> 5;
    int olow = (ob & 31) + hi * 4;
    #pragma unroll
    for (int g = 0; g < 4; ++g) {
        int n = n0 + g * 16 + lo;
        size_t qkbase = ((size_t)(b * NH + h) * NPOS + n) * HD + olow;
        short4e pq, pk;
        #pragma unroll
        for (int r = 0; r < 4; ++r) {
            int o = ob + hi * 4 + r;
            pq[r] = (short)f2bf((aq[g][r] + bq[o]) * QSCALE);
            pk[r] = (short)f2bf(ak[g][r] + bk[o]);
        }
        *(short4e*)&qout[qkbase] = pq;
        *(short4e*)&kout[qkbase] = pk;

        // ---- V store with key permutation pi within the 128-block
        int off = n & 127;               // raw offset in 128-tile
        int G = off >> 4;                // attention key-group 0..7
        int his = lo >> 2, rr = lo & 3;
        int pi;
        if (G < 4) {
            pi = G * 32 + his * 8 + rr;
        } else {
            int gam = G & 3;
            pi = (his >= 2) ? (gam * 32 + (his - 2) * 8 + 4 + rr)
                            : ((gam ^ 1) * 32 + (his + 2) * 8 + 4 + rr);
        }
        int nperm = (n & ~127) | pi;
        size_t vbase = ((size_t)(b * NH + h) * HD + olow) * NPOS + nperm;
        #pragma unroll
        for (int r = 0; r < 4; ++r)
            vout[vbase + (size_t)r * NPOS] = f2bf(av[g][r] + bv[ob + hi * 4 + r]);
    }
}

// ---------------------------------------------------------------------------
// Flash attention partial, bf16 MFMA, 128-key tiles, split-K x3.
// 4 waves/block share K/V tiles staged in LDS via global_load_lds (16B),
// double-buffered, one __syncthreads per tile (T3 minimal template):
//   stage(t+1) -> compute(t) -> barrier(drains vmcnt).
// LDS layout source-pre-swizzled (K: blk^=row&3, V: blk^=row&15) so
// ds_read_b128 fragments hit the structural 8-phase floor.
// Swapped QK^T -> P lane-local; P->bf16 via cvt_pk; PV A-frags via one
// shfl_xor(32) per word with key-permutation pi baked into V storage.
// grid (NSPLIT*16, QT/4): id = x + 48y, 48%8==0 -> all blocks sharing a
// (bh,split) K/V stream land on one XCD (L2 co-location).
// ---------------------------------------------------------------------------
__global__ __launch_bounds__(256) void attn_split(
    const unsigned short* __restrict__ Q,
    const unsigned short* __restrict__ K,
    const unsigned short* __restrict__ V,
    float* __restrict__ Opart,
    float* __restrict__ Lpart)
{
    const int N = NPOS;
    int xb_ = blockIdx.x;           // 0..47: (split, bh)
    int bh = xb_ & 15;
    int split = xb_ >> 4;           // 0..2
    int w = threadIdx.x >> 6;
    int qt = blockIdx.y * 4 + w;    // 0..143
    int n0 = qt * 16;
    int lane = threadIdx.x & 63;
    int lo = lane & 15, hi = lane >> 4;
    bool upperhalf = lane >= 32;

    // double-buffered K/V tiles: 8KB each per buffer (32KB total)
    __shared__ unsigned short Ks[2][128 * HD];
    __shared__ unsigned short Vs[2][HD * 128];

    short8 qa = *(const short8*)(Q + ((size_t)bh * N + n0 + lo) * HD + hi * 8);

    const unsigned short* Kb = K + (size_t)bh * N * HD;
    const unsigned short* Vb = V + (size_t)bh * HD * N;

    short8 ones;
    #pragma unroll
    for (int j = 0; j < 8; ++j) ones[j] = (short)0x3F80;   // bf16 1.0

    f32x4 oacc[2] = {{0.f,0.f,0.f,0.f},{0.f,0.f,0.f,0.f}};
    f32x4 lacc = {0.f,0.f,0.f,0.f};

    const int kbeg = split * KSPAN;

    // ---- staging: wave w covers chunks [w*128, w*128+128) of each 512-chunk tile
    auto stage = [&](int b, int k0) {
        #pragma unroll
        for (int j = 0; j < 2; ++j) {
            int L = w * 128 + j * 64 + lane;           // K chunk: row=L>>2, blk=L&3
            int row = L >> 2, blk = L & 3;
            const unsigned short* src = Kb + (size_t)(k0 + row) * HD + (blk ^ (row & 3)) * 8;
            GLOAD_LDS16(src, &Ks[b][(size_t)(w * 128 + j * 64) * 8]);
        }
        #pragma unroll
        for (int j = 0; j < 2; ++j) {
            int L = w * 128 + j * 64 + lane;           // V chunk: row=L>>4, blk=L&15
            int row = L >> 4, blk = L & 15;
            const unsigned short* src = Vb + (size_t)row * N + k0 + (blk ^ (row & 15)) * 8;
            GLOAD_LDS16(src, &Vs[b][(size_t)(w * 128 + j * 64) * 8]);
        }
    };

    // prologue: stage tile 0
    stage(0, kbeg);
    __syncthreads();                 // drains vmcnt + barrier

    int buf = 0;
    #pragma unroll
    for (int kt = 0; kt < NT; ++kt) {
        int k0 = kbeg + kt * 128;
        if (kt + 1 < NT) stage(buf ^ 1, k0 + 128);

        // ---- S^T = K Q^T from LDS (swizzled read): lane -> P[q=lo][key g*16+hi*4+r]
        f32x4 s[8];
        __builtin_amdgcn_s_setprio(1);
        #pragma unroll
        for (int g = 0; g < 8; ++g) {
            short8 kf = *(const short8*)&Ks[buf][(g * 16 + lo) * HD + (hi ^ (lo & 3)) * 8];
            s[g] = __builtin_amdgcn_mfma_f32_16x16x32_bf16(kf, qa, (f32x4){0.f,0.f,0.f,0.f}, 0, 0, 0);
        }
        __builtin_amdgcn_s_setprio(0);

        // ---- P = 2^S (no max shift; Q carries SCALE*log2e)
        #pragma unroll
        for (int g = 0; g < 8; ++g)
            #pragma unroll
            for (int r = 0; r < 4; ++r)
                s[g][r] = fast_exp2(s[g][r]);

        // ---- pack to bf16 pairs
        unsigned int pk0[8], pk1[8];
        #pragma unroll
        for (int g = 0; g < 8; ++g) {
            pk0[g] = cvt_pk_bf16(s[g][0], s[g][1]);
            pk1[g] = cvt_pk_bf16(s[g][2], s[g][3]);
        }

        // ---- assemble PV A-frags: own groups 0-3 + partner(lane^32) groups 4-7
        #pragma unroll
        for (int c = 0; c < 4; ++c) {
            unsigned int z0 = upperhalf ? pk0[4 + c] : pk0[4 + (c ^ 1)];
            unsigned int z1 = upperhalf ? pk1[4 + c] : pk1[4 + (c ^ 1)];
            unsigned int r0 = (unsigned int)__shfl_xor((int)z0, 32);
            unsigned int r1 = (unsigned int)__shfl_xor((int)z1, 32);
            u32x4 fv = {pk0[c], pk1[c], r0, r1};
            short8 frag = __builtin_bit_cast(short8, fv);

            __builtin_amdgcn_s_setprio(1);
            lacc = __builtin_amdgcn_mfma_f32_16x16x32_bf16(frag, ones, lacc, 0, 0, 0);
            #pragma unroll
            for (int df = 0; df < 2; ++df) {
                short8 vf = *(const short8*)&Vs[buf][(df * 16 + lo) * 128 + ((c * 4 + hi) ^ lo) * 8];
                oacc[df] = __builtin_amdgcn_mfma_f32_16x16x32_bf16(frag, vf, oacc[df], 0, 0, 0);
            }
            __builtin_amdgcn_s_setprio(0);
        }

        __syncthreads();             // all waves done reading buf; stage(buf^1) drained
        buf ^= 1;
    }

    // ---- store partials (unnormalized). Opart tile layout [d=32][row=16].
    size_t tidx  = (((size_t)bh * QT + qt) * NSPLIT + split);
    float* ob = Opart + tidx * (HD * 16);
    #pragma unroll
    for (int df = 0; df < 2; ++df)
        *(f32x4*)&ob[(df * 16 + lo) * 16 + hi * 4] = oacc[df];
    if (lo == 0) {
        float* lb = Lpart + tidx * 16;
        #pragma unroll
        for (int r = 0; r < 4; ++r) lb[hi * 4 + r] = lacc[r];
    }
}

// ---------------------------------------------------------------------------
// Merge split-K partials: omT[b][n][h*32+d] = sum_s Opart / sum_s Lpart.
// ---------------------------------------------------------------------------
__global__ __launch_bounds__(256) void attn_merge(
    const float* __restrict__ Opart,
    const float* __restrict__ Lpart,
    unsigned short* __restrict__ omT)
{
    int bh = blockIdx.y, b = bh >> 3, h = bh & 7;
    int qt = blockIdx.x, n0 = qt * 16;
    int t = threadIdx.x;
    int d = t & 31;
    int r0 = t >> 5;                 // 0..7
    size_t base = ((size_t)bh * QT + qt) * NSPLIT;
    #pragma unroll
    for (int i = 0; i < 2; ++i) {
        int row = r0 + i * 8;
        float osum = 0.f, lsum = 0.f;
        #pragma unroll
        for (int s = 0; s < NSPLIT; ++s) {
            osum += Opart[(base + s) * (HD * 16) + d * 16 + row];
            lsum += Lpart[(base + s) * 16 + row];
        }
        omT[((size_t)b * NPOS + n0 + row) * CH + h * HD + d] = f2bf(osum / lsum);
    }
}

// ---------------------------------------------------------------------------
// Wo GEMM via bf16 MFMA: out fp32 [B][C][N] = Wo . omT^T + bo.
// ---------------------------------------------------------------------------
__global__ __launch_bounds__(256) void wo_gemm(
    const unsigned short* __restrict__ omT,
    const unsigned short* __restrict__ Wo,
    const float* __restrict__ bo,
    float* __restrict__ out)
{
    int b = blockIdx.z;
    int n0 = blockIdx.x * 64;
    int o0 = blockIdx.y * 64;
    int t = threadIdx.x, w = t >> 6, lane = t & 63;
    int lo = lane & 15, hi = lane >> 4;
    int ob = o0 + w * 16;

    const unsigned short* xb = omT + ((size_t)b * NPOS + n0) * CH;

    f32x4 acc[4] = {};
    for (int k0 = 0; k0 < CH; k0 += 32) {
        short8 wf = *(const short8*)&Wo[(size_t)(ob + lo) * CH + k0 + hi * 8];
        #pragma unroll
        for (int g = 0; g < 4; ++g) {
            short8 xf = *(const short8*)&xb[(size_t)(g * 16 + lo) * CH + k0 + hi * 8];
            acc[g] = __builtin_amdgcn_mfma_f32_16x16x32_bf16(wf, xf, acc[g], 0, 0, 0);
        }
    }

    #pragma unroll
    for (int g = 0; g < 4; ++g) {
        int n = n0 + g * 16 + lo;
        #pragma unroll
        for (int r = 0; r < 4; ++r) {
            int o = ob + hi * 4 + r;
            out[((size_t)b * CH + o) * NPOS + n] = acc[g][r] + bo[o];
        }
    }
}

// ---------------------------------------------------------------------------
extern "C" void kernel_launch(void* const* d_in, const int* in_sizes, int n_in,
                              void* d_out, int out_size, void* d_ws, size_t ws_size,
                              hipStream_t stream) {
    const float* x  = (const float*)d_in[0];
    const float* Wq = (const float*)d_in[1];
    const float* bq = (const float*)d_in[2];
    const float* Wk = (const float*)d_in[3];
    const float* bk = (const float*)d_in[4];
    const float* Wv = (const float*)d_in[5];
    const float* bv = (const float*)d_in[6];
    const float* Wo = (const float*)d_in[7];
    const float* bo = (const float*)d_in[8];
    float* out = (float*)d_out;

    const size_t E  = (size_t)BATCH * CH * NPOS;   // 1,179,648
    const size_t WS = (size_t)CH * CH;             // 65,536
    unsigned short* wbf = (unsigned short*)d_ws;   // 4 weight matrices bf16
    unsigned short* xT  = wbf + 4 * WS;            // [B][N][C] bf16
    unsigned short* qb  = xT + E;                  // [bh][N][32] bf16 (QSCALE'd)
    unsigned short* kb  = qb + E;                  // [bh][N][32] bf16
    unsigned short* vT  = kb + E;                  // [bh][32][N] bf16 (pi-permuted)
    float* Opart = (float*)(vT + E);               // 16*QT*NSPLIT*512 f32
    float* Lpart = Opart + (size_t)16 * QT * NSPLIT * (HD * 16);
    unsigned short* om = xT;                       // alias: xT dead after qkv_gemm
    (void)ws_size; (void)in_sizes; (void)n_in; (void)out_size;

    hipLaunchKernelGGL(convert_w, dim3(64, 4), dim3(256), 0, stream,
                       Wq, Wk, Wv, Wo, wbf);
    hipLaunchKernelGGL(transpose_x, dim3(NPOS / 32, CH / 32, BATCH), dim3(256), 0, stream,
                       x, xT);
    hipLaunchKernelGGL(qkv_gemm, dim3(NPOS / 64, CH / 64, BATCH), dim3(256), 0, stream,
                       xT, wbf, bq, bk, bv, qb, kb, vT);
    hipLaunchKernelGGL(attn_split, dim3(NSPLIT * 16, QT / 4), dim3(256), 0, stream,
                       qb, kb, vT, Opart, Lpart);
    hipLaunchKernelGGL(attn_merge, dim3(QT, BATCH * NH), dim3(256), 0, stream,
                       Opart, Lpart, om);
    hipLaunchKernelGGL(wo_gemm, dim3(NPOS / 64, CH / 64, BATCH), dim3(256), 0, stream,
                       om, wbf + 3 * WS, bo, out);
}

// Round 8
// 71.308 us; speedup vs baseline: 1.9709x; 1.0625x over previous
//
#include <hip/hip_runtime.h>
#include <hip/hip_bf16.h>

// Problem constants
#define BATCH 2
#define CH 256
#define NH 8
#define HD 32
#define NPOS 2304            // 48*48
#define SCALE 0.17677669529663687f          // 32^-0.5
#define QSCALE 0.25503482f                  // SCALE * log2(e)
#define NSPLIT 3
#define KSPAN (NPOS / NSPLIT)               // 768 = 6 tiles of 128
#define NT (KSPAN / 128)                    // 6
#define QT (NPOS / 16)                      // 144 q-tiles

typedef __attribute__((ext_vector_type(8))) short short8;   // 8 x bf16 (4 VGPRs)
typedef __attribute__((ext_vector_type(4))) short short4e;  // 4 x bf16 (8B)
typedef __attribute__((ext_vector_type(4))) float f32x4;
typedef __attribute__((ext_vector_type(4))) unsigned int u32x4;

__device__ __forceinline__ unsigned short f2bf(float f) {
    unsigned int u = __builtin_bit_cast(unsigned int, f);
    u += 0x7FFFu + ((u >> 16) & 1u);     // round-to-nearest-even
    return (unsigned short)(u >> 16);
}

// packed 2xbf16 <- 2xf32 (D.lo = cvt(a), D.hi = cvt(b)), RNE
__device__ __forceinline__ unsigned int cvt_pk_bf16(float a, float b) {
    unsigned int r;
    asm("v_cvt_pk_bf16_f32 %0, %1, %2" : "=v"(r) : "v"(a), "v"(b));
    return r;
}

// single-instruction 2^x
__device__ __forceinline__ float fast_exp2(float x) {
    float r;
    asm("v_exp_f32 %0, %1" : "=v"(r) : "v"(x));
    return r;
}

// async global->LDS, 16B per lane; LDS dest = uniform base + lane*16
#define GLOAD_LDS16(gsrc, ldst) \
    __builtin_amdgcn_global_load_lds( \
        (const __attribute__((address_space(1))) void*)(gsrc), \
        (__attribute__((address_space(3))) void*)(ldst), 16, 0, 0)

// ---------------------------------------------------------------------------
// Prep: fused weight-convert (blocks 0..255) + x transpose (blocks 256..1407).
// convert: 4 x [256x256] fp32 W -> bf16 concat.   transpose: x [B][C][N] fp32
// -> xT [B][N][C] bf16 via 32x32 LDS tiles.
// ---------------------------------------------------------------------------
__global__ __launch_bounds__(256) void prep(
    const float* __restrict__ Wq, const float* __restrict__ Wk,
    const float* __restrict__ Wv, const float* __restrict__ Wo,
    const float* __restrict__ x,
    unsigned short* __restrict__ wbf, unsigned short* __restrict__ xT)
{
    __shared__ float Ts[32][33];
    int id = blockIdx.x;
    int t = threadIdx.x;
    if (id < 256) {
        int which = id >> 6;
        const float* src = (which == 0) ? Wq : (which == 1) ? Wk : (which == 2) ? Wv : Wo;
        unsigned short* d = wbf + (size_t)which * CH * CH;
        int i = ((id & 63) * 256 + t) * 4;
        f32x4 v = *(const f32x4*)&src[i];
        short4e o;
        #pragma unroll
        for (int j = 0; j < 4; ++j) o[j] = (short)f2bf(v[j]);
        *(short4e*)&d[i] = o;
    } else {
        int tid = id - 256;
        int b = tid / 576;
        int rem = tid % 576;
        int c0 = (rem / 72) * 32;
        int n0 = (rem % 72) * 32;
        int col = t & 31, row = t >> 5;      // row 0..7
        #pragma unroll
        for (int i = 0; i < 4; ++i)
            Ts[row + i * 8][col] = x[((size_t)b * CH + c0 + row + i * 8) * NPOS + n0 + col];
        __syncthreads();
        #pragma unroll
        for (int i = 0; i < 4; ++i)
            xT[((size_t)b * NPOS + n0 + row + i * 8) * CH + c0 + col] = f2bf(Ts[col][row + i * 8]);
    }
}

// ---------------------------------------------------------------------------
// Fused QKV GEMM via bf16 MFMA. xT: [B][N][C] bf16. Wb: q|k|v bf16 [o][c].
// q,k bf16 [(b*NH+h)*N + n]*32 + d   (q pre-scaled by QSCALE = SCALE*log2e)
// v  bf16 [(b*NH+h)*32 + d]*N + pi(n)   (transposed, key-permuted per 128-blk)
// Block = 4 waves, tile 32o x 64n; wave owns 16o x 32n. Grid 576 blocks.
// ---------------------------------------------------------------------------
__global__ __launch_bounds__(256) void qkv_gemm(
    const unsigned short* __restrict__ xT,
    const unsigned short* __restrict__ Wb,
    const float* __restrict__ bq, const float* __restrict__ bk,
    const float* __restrict__ bv,
    unsigned short* __restrict__ qout, unsigned short* __restrict__ kout,
    unsigned short* __restrict__ vout)
{
    int b = blockIdx.z;
    int n0 = blockIdx.x * 64;            // 36
    int o0 = blockIdx.y * 32;            // 8
    int t = threadIdx.x, w = t >> 6, lane = t & 63;
    int lo = lane & 15, hi = lane >> 4;
    int ob = o0 + (w & 1) * 16;
    int nb = n0 + (w >> 1) * 32;

    const unsigned short* Wq = Wb;
    const unsigned short* Wk = Wb + (size_t)CH * CH;
    const unsigned short* Wv = Wb + (size_t)2 * CH * CH;
    const unsigned short* xb = xT + ((size_t)b * NPOS + nb) * CH;

    f32x4 aq[2] = {}, ak[2] = {}, av[2] = {};

    for (int k0 = 0; k0 < CH; k0 += 32) {
        short8 wqf = *(const short8*)&Wq[(size_t)(ob + lo) * CH + k0 + hi * 8];
        short8 wkf = *(const short8*)&Wk[(size_t)(ob + lo) * CH + k0 + hi * 8];
        short8 wvf = *(const short8*)&Wv[(size_t)(ob + lo) * CH + k0 + hi * 8];
        #pragma unroll
        for (int g = 0; g < 2; ++g) {
            short8 xf = *(const short8*)&xb[(size_t)(g * 16 + lo) * CH + k0 + hi * 8];
            aq[g] = __builtin_amdgcn_mfma_f32_16x16x32_bf16(wqf, xf, aq[g], 0, 0, 0);
            ak[g] = __builtin_amdgcn_mfma_f32_16x16x32_bf16(wkf, xf, ak[g], 0, 0, 0);
            av[g] = __builtin_amdgcn_mfma_f32_16x16x32_bf16(wvf, xf, av[g], 0, 0, 0);
        }
    }

    int h = ob >> 5;
    int olow = (ob & 31) + hi * 4;
    #pragma unroll
    for (int g = 0; g < 2; ++g) {
        int n = nb + g * 16 + lo;
        size_t qkbase = ((size_t)(b * NH + h) * NPOS + n) * HD + olow;
        short4e pq, pk;
        #pragma unroll
        for (int r = 0; r < 4; ++r) {
            int o = ob + hi * 4 + r;
            pq[r] = (short)f2bf((aq[g][r] + bq[o]) * QSCALE);
            pk[r] = (short)f2bf(ak[g][r] + bk[o]);
        }
        *(short4e*)&qout[qkbase] = pq;
        *(short4e*)&kout[qkbase] = pk;

        // ---- V store with key permutation pi within the 128-block
        int off = n & 127;               // raw offset in 128-tile
        int G = off >> 4;                // attention key-group 0..7
        int his = lo >> 2, rr = lo & 3;
        int pi;
        if (G < 4) {
            pi = G * 32 + his * 8 + rr;
        } else {
            int gam = G & 3;
            pi = (his >= 2) ? (gam * 32 + (his - 2) * 8 + 4 + rr)
                            : ((gam ^ 1) * 32 + (his + 2) * 8 + 4 + rr);
        }
        int nperm = (n & ~127) | pi;
        size_t vbase = ((size_t)(b * NH + h) * HD + olow) * NPOS + nperm;
        #pragma unroll
        for (int r = 0; r < 4; ++r)
            vout[vbase + (size_t)r * NPOS] = f2bf(av[g][r] + bv[ob + hi * 4 + r]);
    }
}

// ---------------------------------------------------------------------------
// Flash attention partial, bf16 MFMA, 128-key tiles, split-K x3.
// 4 waves/block share K/V tiles staged in LDS via global_load_lds (16B),
// double-buffered, one __syncthreads per tile:
//   stage(t+1) -> compute(t) -> barrier(drains vmcnt).
// LDS source-pre-swizzled (K: blk^=row&3, V: blk^=row&15); swapped QK^T ->
// P lane-local; cvt_pk + one shfl_xor(32)/word with pi baked into V storage.
// grid (48, 36): id = x + 48y, 48%8==0 -> same (bh,split) -> same XCD.
// ---------------------------------------------------------------------------
__global__ __launch_bounds__(256) void attn_split(
    const unsigned short* __restrict__ Q,
    const unsigned short* __restrict__ K,
    const unsigned short* __restrict__ V,
    float* __restrict__ Opart,
    float* __restrict__ Lpart)
{
    const int N = NPOS;
    int xb_ = blockIdx.x;           // 0..47: (split, bh)
    int bh = xb_ & 15;
    int split = xb_ >> 4;           // 0..2
    int w = threadIdx.x >> 6;
    int qt = blockIdx.y * 4 + w;    // 0..143
    int n0 = qt * 16;
    int lane = threadIdx.x & 63;
    int lo = lane & 15, hi = lane >> 4;
    bool upperhalf = lane >= 32;

    // double-buffered K/V tiles: 8KB each per buffer (32KB total)
    __shared__ unsigned short Ks[2][128 * HD];
    __shared__ unsigned short Vs[2][HD * 128];

    short8 qa = *(const short8*)(Q + ((size_t)bh * N + n0 + lo) * HD + hi * 8);

    const unsigned short* Kb = K + (size_t)bh * N * HD;
    const unsigned short* Vb = V + (size_t)bh * HD * N;

    short8 ones;
    #pragma unroll
    for (int j = 0; j < 8; ++j) ones[j] = (short)0x3F80;   // bf16 1.0

    f32x4 oacc[2] = {{0.f,0.f,0.f,0.f},{0.f,0.f,0.f,0.f}};
    f32x4 lacc = {0.f,0.f,0.f,0.f};

    const int kbeg = split * KSPAN;

    // ---- staging: wave w covers chunks [w*128, w*128+128) of each 512-chunk tile
    auto stage = [&](int b, int k0) {
        #pragma unroll
        for (int j = 0; j < 2; ++j) {
            int L = w * 128 + j * 64 + lane;           // K chunk: row=L>>2, blk=L&3
            int row = L >> 2, blk = L & 3;
            const unsigned short* src = Kb + (size_t)(k0 + row) * HD + (blk ^ (row & 3)) * 8;
            GLOAD_LDS16(src, &Ks[b][(size_t)(w * 128 + j * 64) * 8]);
        }
        #pragma unroll
        for (int j = 0; j < 2; ++j) {
            int L = w * 128 + j * 64 + lane;           // V chunk: row=L>>4, blk=L&15
            int row = L >> 4, blk = L & 15;
            const unsigned short* src = Vb + (size_t)row * N + k0 + (blk ^ (row & 15)) * 8;
            GLOAD_LDS16(src, &Vs[b][(size_t)(w * 128 + j * 64) * 8]);
        }
    };

    // prologue: stage tile 0
    stage(0, kbeg);
    __syncthreads();                 // drains vmcnt + barrier

    int buf = 0;
    #pragma unroll
    for (int kt = 0; kt < NT; ++kt) {
        int k0 = kbeg + kt * 128;
        if (kt + 1 < NT) stage(buf ^ 1, k0 + 128);

        // ---- S^T = K Q^T from LDS (swizzled read): lane -> P[q=lo][key g*16+hi*4+r]
        f32x4 s[8];
        __builtin_amdgcn_s_setprio(1);
        #pragma unroll
        for (int g = 0; g < 8; ++g) {
            short8 kf = *(const short8*)&Ks[buf][(g * 16 + lo) * HD + (hi ^ (lo & 3)) * 8];
            s[g] = __builtin_amdgcn_mfma_f32_16x16x32_bf16(kf, qa, (f32x4){0.f,0.f,0.f,0.f}, 0, 0, 0);
        }
        __builtin_amdgcn_s_setprio(0);

        // ---- P = 2^S (no max shift; Q carries SCALE*log2e)
        #pragma unroll
        for (int g = 0; g < 8; ++g)
            #pragma unroll
            for (int r = 0; r < 4; ++r)
                s[g][r] = fast_exp2(s[g][r]);

        // ---- pack to bf16 pairs
        unsigned int pk0[8], pk1[8];
        #pragma unroll
        for (int g = 0; g < 8; ++g) {
            pk0[g] = cvt_pk_bf16(s[g][0], s[g][1]);
            pk1[g] = cvt_pk_bf16(s[g][2], s[g][3]);
        }

        // ---- assemble PV A-frags: own groups 0-3 + partner(lane^32) groups 4-7
        __builtin_amdgcn_s_setprio(1);
        #pragma unroll
        for (int c = 0; c < 4; ++c) {
            unsigned int z0 = upperhalf ? pk0[4 + c] : pk0[4 + (c ^ 1)];
            unsigned int z1 = upperhalf ? pk1[4 + c] : pk1[4 + (c ^ 1)];
            unsigned int r0 = (unsigned int)__shfl_xor((int)z0, 32);
            unsigned int r1 = (unsigned int)__shfl_xor((int)z1, 32);
            u32x4 fv = {pk0[c], pk1[c], r0, r1};
            short8 frag = __builtin_bit_cast(short8, fv);

            lacc = __builtin_amdgcn_mfma_f32_16x16x32_bf16(frag, ones, lacc, 0, 0, 0);
            #pragma unroll
            for (int df = 0; df < 2; ++df) {
                short8 vf = *(const short8*)&Vs[buf][(df * 16 + lo) * 128 + ((c * 4 + hi) ^ lo) * 8];
                oacc[df] = __builtin_amdgcn_mfma_f32_16x16x32_bf16(frag, vf, oacc[df], 0, 0, 0);
            }
        }
        __builtin_amdgcn_s_setprio(0);

        __syncthreads();             // all waves done reading buf; stage(buf^1) drained
        buf ^= 1;
    }

    // ---- store partials (unnormalized). Opart tile layout [d=32][row=16].
    size_t tidx  = (((size_t)bh * QT + qt) * NSPLIT + split);
    float* ob = Opart + tidx * (HD * 16);
    #pragma unroll
    for (int df = 0; df < 2; ++df)
        *(f32x4*)&ob[(df * 16 + lo) * 16 + hi * 4] = oacc[df];
    if (lo == 0) {
        float* lb = Lpart + tidx * 16;
        #pragma unroll
        for (int r = 0; r < 4; ++r) lb[hi * 4 + r] = lacc[r];
    }
}

// ---------------------------------------------------------------------------
// Merge split-K partials: omT[b][n][h*32+d] = sum_s Opart / sum_s Lpart.
// ---------------------------------------------------------------------------
__global__ __launch_bounds__(256) void attn_merge(
    const float* __restrict__ Opart,
    const float* __restrict__ Lpart,
    unsigned short* __restrict__ omT)
{
    int bh = blockIdx.y, b = bh >> 3, h = bh & 7;
    int qt = blockIdx.x, n0 = qt * 16;
    int t = threadIdx.x;
    int d = t & 31;
    int r0 = t >> 5;                 // 0..7
    size_t base = ((size_t)bh * QT + qt) * NSPLIT;
    #pragma unroll
    for (int i = 0; i < 2; ++i) {
        int row = r0 + i * 8;
        float osum = 0.f, lsum = 0.f;
        #pragma unroll
        for (int s = 0; s < NSPLIT; ++s) {
            osum += Opart[(base + s) * (HD * 16) + d * 16 + row];
            lsum += Lpart[(base + s) * 16 + row];
        }
        omT[((size_t)b * NPOS + n0 + row) * CH + h * HD + d] = f2bf(osum / lsum);
    }
}

// ---------------------------------------------------------------------------
// Wo GEMM via bf16 MFMA: out fp32 [B][C][N] = Wo . omT^T + bo.
// Block = 4 waves, tile 32o x 64n; wave owns 16o x 32n. Grid 576 blocks.
// ---------------------------------------------------------------------------
__global__ __launch_bounds__(256) void wo_gemm(
    const unsigned short* __restrict__ omT,
    const unsigned short* __restrict__ Wo,
    const float* __restrict__ bo,
    float* __restrict__ out)
{
    int b = blockIdx.z;
    int n0 = blockIdx.x * 64;            // 36
    int o0 = blockIdx.y * 32;            // 8
    int t = threadIdx.x, w = t >> 6, lane = t & 63;
    int lo = lane & 15, hi = lane >> 4;
    int ob = o0 + (w & 1) * 16;
    int nb = n0 + (w >> 1) * 32;

    const unsigned short* xb = omT + ((size_t)b * NPOS + nb) * CH;

    f32x4 acc[2] = {};
    for (int k0 = 0; k0 < CH; k0 += 32) {
        short8 wf = *(const short8*)&Wo[(size_t)(ob + lo) * CH + k0 + hi * 8];
        #pragma unroll
        for (int g = 0; g < 2; ++g) {
            short8 xf = *(const short8*)&xb[(size_t)(g * 16 + lo) * CH + k0 + hi * 8];
            acc[g] = __builtin_amdgcn_mfma_f32_16x16x32_bf16(wf, xf, acc[g], 0, 0, 0);
        }
    }

    #pragma unroll
    for (int g = 0; g < 2; ++g) {
        int n = nb + g * 16 + lo;
        #pragma unroll
        for (int r = 0; r < 4; ++r) {
            int o = ob + hi * 4 + r;
            out[((size_t)b * CH + o) * NPOS + n] = acc[g][r] + bo[o];
        }
    }
}

// ---------------------------------------------------------------------------
extern "C" void kernel_launch(void* const* d_in, const int* in_sizes, int n_in,
                              void* d_out, int out_size, void* d_ws, size_t ws_size,
                              hipStream_t stream) {
    const float* x  = (const float*)d_in[0];
    const float* Wq = (const float*)d_in[1];
    const float* bq = (const float*)d_in[2];
    const float* Wk = (const float*)d_in[3];
    const float* bk = (const float*)d_in[4];
    const float* Wv = (const float*)d_in[5];
    const float* bv = (const float*)d_in[6];
    const float* Wo = (const float*)d_in[7];
    const float* bo = (const float*)d_in[8];
    float* out = (float*)d_out;

    const size_t E  = (size_t)BATCH * CH * NPOS;   // 1,179,648
    const size_t WS = (size_t)CH * CH;             // 65,536
    unsigned short* wbf = (unsigned short*)d_ws;   // 4 weight matrices bf16
    unsigned short* xT  = wbf + 4 * WS;            // [B][N][C] bf16
    unsigned short* qb  = xT + E;                  // [bh][N][32] bf16 (QSCALE'd)
    unsigned short* kb  = qb + E;                  // [bh][N][32] bf16
    unsigned short* vT  = kb + E;                  // [bh][32][N] bf16 (pi-permuted)
    float* Opart = (float*)(vT + E);               // 16*QT*NSPLIT*512 f32
    float* Lpart = Opart + (size_t)16 * QT * NSPLIT * (HD * 16);
    unsigned short* om = xT;                       // alias: xT dead after qkv_gemm
    (void)ws_size; (void)in_sizes; (void)n_in; (void)out_size;

    hipLaunchKernelGGL(prep, dim3(256 + 1152), dim3(256), 0, stream,
                       Wq, Wk, Wv, Wo, x, wbf, xT);
    hipLaunchKernelGGL(qkv_gemm, dim3(NPOS / 64, CH / 32, BATCH), dim3(256), 0, stream,
                       xT, wbf, bq, bk, bv, qb, kb, vT);
    hipLaunchKernelGGL(attn_split, dim3(NSPLIT * 16, QT / 4), dim3(256), 0, stream,
                       qb, kb, vT, Opart, Lpart);
    hipLaunchKernelGGL(attn_merge, dim3(QT, BATCH * NH), dim3(256), 0, stream,
                       Opart, Lpart, om);
    hipLaunchKernelGGL(wo_gemm, dim3(NPOS / 64, CH / 32, BATCH), dim3(256), 0, stream,
                       om, wbf + 3 * WS, bo, out);
}